// Round 1
// baseline (241.254 us; speedup 1.0000x reference)
//
#include <hip/hip_runtime.h>

typedef _Float16 f16;
typedef _Float16 f16x8 __attribute__((ext_vector_type(8)));
typedef _Float16 f16x2 __attribute__((ext_vector_type(2)));
typedef float f32x4 __attribute__((ext_vector_type(4)));
typedef float f32x2 __attribute__((ext_vector_type(2)));

#define MFMA16(a, b, c) __builtin_amdgcn_mfma_f32_16x16x32_f16(a, b, c, 0, 0, 0)

#define HID 4096
#define ROWS 128      // B*S
#define SCL 0.12751743f  // (1/sqrt(128)) * log2(e)

__device__ __forceinline__ f16x8 cvt8(float4 x, float4 y) {
    f16x8 v = {(f16)x.x, (f16)x.y, (f16)x.z, (f16)x.w,
               (f16)y.x, (f16)y.y, (f16)y.z, (f16)y.w};
    return v;
}

// XOR swizzle for a tile with 128 f16 (256 B) row pitch
__device__ __forceinline__ int swz2(int row, int cb) {
    return row * 256 + (cb ^ ((row & 7) << 4));
}

// ---------------- kernel 0: h fp32 -> f16 ----------------
__global__ void k_cvt(const float* __restrict__ src, f16* __restrict__ dst) {
    const int i = blockIdx.x * blockDim.x + threadIdx.x;  // 65536 threads
    const float4* s4 = (const float4*)src + (size_t)i * 2;
    float4 x = s4[0], y = s4[1];
    *((f16x8*)dst + i) = cvt8(x, y);
}

// ---------------- kernel A: fused QKV projection ----------------
// out[r][c] = sum_k h[r][k] * W[c][k];  M=128, N(tile)=16, K=4096, BK=128
__global__ __launch_bounds__(256) void k_proj(
        const f16* __restrict__ hb,
        const float* __restrict__ Wq, const float* __restrict__ Wk,
        const float* __restrict__ Wv,
        f16* __restrict__ Qw, f16* __restrict__ Kw, f16* __restrict__ Vw) {
    const int mat = blockIdx.x >> 8;     // 0..2
    const int ct  = blockIdx.x & 255;    // 256 col tiles of 16
    const float* __restrict__ W = (mat == 0) ? Wq : (mat == 1) ? Wk : Wv;
    f16* __restrict__ Ob = (mat == 0) ? Qw : (mat == 1) ? Kw : Vw;
    const int c0 = ct * 16;

    __shared__ __align__(16) f16 sA[128 * 128];  // 32 KB, swizzled
    __shared__ __align__(16) f16 sB[16 * 128];   // 4 KB, swizzled

    const int tid = threadIdx.x;
    const int w = tid >> 6, l = tid & 63;
    const int rw = w * 32;
    const int ar = tid >> 4;          // 0..15
    const int ac = (tid & 15) * 8;    // element col

    f32x4 acc0 = {}, acc1 = {};

    for (int ks = 0; ks < 32; ++ks) {
        const int k0 = ks * 128;
        // stage A (h): 128 x 128 f16
        #pragma unroll
        for (int c = 0; c < 8; ++c) {
            const int row = c * 16 + ar;
            f16x8 v = *(const f16x8*)(hb + (size_t)row * HID + k0 + ac);
            *(f16x8*)((char*)sA + swz2(row, ac * 2)) = v;
        }
        // stage B (W): 16 x 128, fp32 -> f16
        {
            const float* wp = W + (size_t)(c0 + ar) * HID + k0 + ac;
            float4 x = *(const float4*)wp;
            float4 y = *(const float4*)(wp + 4);
            *(f16x8*)((char*)sB + swz2(ar, ac * 2)) = cvt8(x, y);
        }
        __syncthreads();
        #pragma unroll
        for (int kk = 0; kk < 4; ++kk) {
            const int cb = kk * 64 + (l >> 4) * 16;
            f16x8 a0 = *(const f16x8*)((char*)sA + swz2(rw + (l & 15), cb));
            f16x8 a1 = *(const f16x8*)((char*)sA + swz2(rw + 16 + (l & 15), cb));
            f16x8 b0 = *(const f16x8*)((char*)sB + swz2((l & 15), cb));
            acc0 = MFMA16(a0, b0, acc0);
            acc1 = MFMA16(a1, b0, acc1);
        }
        __syncthreads();
    }
    #pragma unroll
    for (int r = 0; r < 4; ++r) {
        const int col = c0 + (l & 15);
        Ob[(size_t)(rw + (l >> 4) * 4 + r) * HID + col]      = (f16)acc0[r];
        Ob[(size_t)(rw + 16 + (l >> 4) * 4 + r) * HID + col] = (f16)acc1[r];
    }
}

// ---------------- kernel B: flash attention, 1 block per (b,h) ----------------
__global__ __launch_bounds__(1024) void k_attn(
        const f16* __restrict__ Qw, const f16* __restrict__ Kw,
        const f16* __restrict__ Vw,
        const float* __restrict__ Kc, const float* __restrict__ Vc,
        const int* __restrict__ posp, f16* __restrict__ Ow) {

    // smem: during loop -> per-wave P buffers (16 waves * 16x40 f16 = 20 KB)
    //       after loop  -> Osh 128 KB + Msh/Lsh 2 KB (barrier separates uses)
    __shared__ __align__(16) char smem[131072 + 2048];

    const int bh = blockIdx.x;
    const int b = bh >> 5, hh = bh & 31;
    const int tid = threadIdx.x, w = tid >> 6, l = tid & 63;
    const int pos = *posp;
    const int ntiles = (pos + 16 + 31) >> 5;

    const float* Kb = Kc + (size_t)bh * (4096 * 128);
    const float* Vb = Vc + (size_t)bh * (4096 * 128);

    // Q fragments: lane holds Q[s=l&15][d = kk*32 + (l>>4)*8 + j]
    f16x8 qf[4];
    {
        const f16* qp = Qw + (size_t)(b * 16 + (l & 15)) * HID + hh * 128 + (l >> 4) * 8;
        #pragma unroll
        for (int kk = 0; kk < 4; ++kk) qf[kk] = *(const f16x8*)(qp + kk * 32);
    }

    f32x4 o[8] = {};
    float m[4], lsum[4];
    #pragma unroll
    for (int r = 0; r < 4; ++r) { m[r] = -3e38f; lsum[r] = 0.f; }

    f16* Pw = (f16*)smem + w * 640;  // 16 rows x 40 f16 pitch

    for (int tau = w; tau < ntiles; tau += 16) {
        const int t0 = tau * 32;
        const bool pure = (t0 + 32 <= pos);
        f32x4 sa[2] = {};

        // ---- QK^T: D[s][t], B-frag = K rows ----
        if (pure) {
            #pragma unroll
            for (int tn = 0; tn < 2; ++tn) {
                const float* kp = Kb + (size_t)(t0 + tn * 16 + (l & 15)) * 128 + (l >> 4) * 8;
                #pragma unroll
                for (int kk = 0; kk < 4; ++kk) {
                    float4 x = *(const float4*)(kp + kk * 32);
                    float4 y = *(const float4*)(kp + kk * 32 + 4);
                    sa[tn] = MFMA16(qf[kk], cvt8(x, y), sa[tn]);
                }
            }
        } else {
            #pragma unroll
            for (int tn = 0; tn < 2; ++tn) {
                const int trow = t0 + tn * 16 + (l & 15);
                f16x8 kf[4];
                if (trow < pos) {
                    const float* kp = Kb + (size_t)trow * 128 + (l >> 4) * 8;
                    #pragma unroll
                    for (int kk = 0; kk < 4; ++kk) {
                        float4 x = *(const float4*)(kp + kk * 32);
                        float4 y = *(const float4*)(kp + kk * 32 + 4);
                        kf[kk] = cvt8(x, y);
                    }
                } else {
                    const int tt = trow - pos;
                    const int rr = tt < 15 ? tt : 15;
                    const f16* kp = Kw + (size_t)(b * 16 + rr) * HID + hh * 128 + (l >> 4) * 8;
                    #pragma unroll
                    for (int kk = 0; kk < 4; ++kk) kf[kk] = *(const f16x8*)(kp + kk * 32);
                }
                #pragma unroll
                for (int kk = 0; kk < 4; ++kk) sa[tn] = MFMA16(qf[kk], kf[kk], sa[tn]);
            }
        }

        // ---- scale + causal/validity mask ----
        float sc[2][4];
        #pragma unroll
        for (int tn = 0; tn < 2; ++tn)
            #pragma unroll
            for (int r = 0; r < 4; ++r) sc[tn][r] = sa[tn][r] * SCL;
        if (!pure) {
            #pragma unroll
            for (int tn = 0; tn < 2; ++tn) {
                const int tg = t0 + tn * 16 + (l & 15);
                if (tg >= pos) {
                    const int tt = tg - pos;
                    #pragma unroll
                    for (int r = 0; r < 4; ++r) {
                        const int s_ = (l >> 4) * 4 + r;
                        if (tt > s_ || tt >= 16) sc[tn][r] = -3e38f;
                    }
                }
            }
        }

        // ---- online softmax (rows live on regs; 16-lane groups hold a row) ----
        float vmax[4];
        #pragma unroll
        for (int r = 0; r < 4; ++r) vmax[r] = fmaxf(sc[0][r], sc[1][r]);
        #pragma unroll
        for (int d = 1; d < 16; d <<= 1)
            #pragma unroll
            for (int r = 0; r < 4; ++r) vmax[r] = fmaxf(vmax[r], __shfl_xor(vmax[r], d));
        float p[2][4], rs[4], fac[4];
        #pragma unroll
        for (int r = 0; r < 4; ++r) {
            const float mn = fmaxf(m[r], vmax[r]);
            fac[r] = exp2f(m[r] - mn);
            m[r] = mn;
            p[0][r] = sc[0][r] < -1e29f ? 0.f : exp2f(sc[0][r] - mn);
            p[1][r] = sc[1][r] < -1e29f ? 0.f : exp2f(sc[1][r] - mn);
            rs[r] = p[0][r] + p[1][r];
            lsum[r] *= fac[r];
        }
        #pragma unroll
        for (int d = 1; d < 16; d <<= 1)
            #pragma unroll
            for (int r = 0; r < 4; ++r) rs[r] += __shfl_xor(rs[r], d);
        #pragma unroll
        for (int r = 0; r < 4; ++r) lsum[r] += rs[r];
        #pragma unroll
        for (int dt = 0; dt < 8; ++dt)
            #pragma unroll
            for (int r = 0; r < 4; ++r) o[dt][r] *= fac[r];

        // ---- P: D-layout -> A-frag layout via per-wave LDS ----
        #pragma unroll
        for (int r = 0; r < 4; ++r) {
            const int s_ = (l >> 4) * 4 + r;
            Pw[s_ * 40 + (l & 15)]      = (f16)p[0][r];
            Pw[s_ * 40 + 16 + (l & 15)] = (f16)p[1][r];
        }
        asm volatile("s_waitcnt lgkmcnt(0)" ::: "memory");
        f16x8 pa = *(const f16x8*)(Pw + (l & 15) * 40 + (l >> 4) * 8);

        // ---- PV: B-frag = V[t][d], K=32 = this tile ----
        if (pure) {
            const float* vp = Vb + (size_t)(t0 + (l >> 4) * 8) * 128 + (l & 15);
            #pragma unroll
            for (int dt = 0; dt < 8; ++dt) {
                f16x8 vf;
                #pragma unroll
                for (int j = 0; j < 8; ++j) vf[j] = (f16)vp[j * 128 + dt * 16];
                o[dt] = MFMA16(pa, vf, o[dt]);
            }
        } else {
            const int tb = t0 + (l >> 4) * 8;
            #pragma unroll
            for (int dt = 0; dt < 8; ++dt) {
                f16x8 vf;
                #pragma unroll
                for (int j = 0; j < 8; ++j) {
                    const int t = tb + j;
                    if (t < pos) {
                        vf[j] = (f16)Vb[(size_t)t * 128 + dt * 16 + (l & 15)];
                    } else {
                        const int rr = (t - pos < 15) ? (t - pos) : 15;
                        vf[j] = Vw[(size_t)(b * 16 + rr) * HID + hh * 128 + dt * 16 + (l & 15)];
                    }
                }
                o[dt] = MFMA16(pa, vf, o[dt]);
            }
        }
    }

    // ---- merge 16 per-wave partials ----
    __syncthreads();  // everyone done with Pw region (aliases Osh)
    float* Osh = (float*)smem;                 // [16][16][128]
    float* Msh = (float*)(smem + 131072);      // [16][16]
    float* Lsh = Msh + 256;
    #pragma unroll
    for (int dt = 0; dt < 8; ++dt)
        #pragma unroll
        for (int r = 0; r < 4; ++r)
            Osh[w * 2048 + ((l >> 4) * 4 + r) * 128 + dt * 16 + (l & 15)] = o[dt][r];
    if ((l & 15) == 0) {
        #pragma unroll
        for (int r = 0; r < 4; ++r) {
            Msh[w * 16 + (l >> 4) * 4 + r] = m[r];
            Lsh[w * 16 + (l >> 4) * 4 + r] = lsum[r];
        }
    }
    __syncthreads();
    {
        const int s_ = tid >> 6;
        const int d_ = (tid & 63) * 2;
        float M = -3e38f;
        #pragma unroll
        for (int ww = 0; ww < 16; ++ww) M = fmaxf(M, Msh[ww * 16 + s_]);
        float L = 0.f, o0 = 0.f, o1 = 0.f;
        #pragma unroll
        for (int ww = 0; ww < 16; ++ww) {
            const float e = exp2f(Msh[ww * 16 + s_] - M);
            L += e * Lsh[ww * 16 + s_];
            f32x2 v = *(const f32x2*)(Osh + ww * 2048 + s_ * 128 + d_);
            o0 += e * v.x;
            o1 += e * v.y;
        }
        const float inv = 1.f / L;
        f16x2 res = {(f16)(o0 * inv), (f16)(o1 * inv)};
        *(f16x2*)(Ow + (size_t)(b * 16 + s_) * HID + hh * 128 + d_) = res;
    }
}

// ---------------- kernel C: output projection ----------------
__global__ __launch_bounds__(256) void k_oproj(
        const f16* __restrict__ Oa, const float* __restrict__ Wo,
        float* __restrict__ out) {
    const int c0 = blockIdx.x * 16;  // 256 col tiles

    __shared__ __align__(16) f16 sA[128 * 128];
    __shared__ __align__(16) f16 sB[16 * 128];

    const int tid = threadIdx.x;
    const int w = tid >> 6, l = tid & 63;
    const int rw = w * 32;
    const int ar = tid >> 4;
    const int ac = (tid & 15) * 8;

    f32x4 acc0 = {}, acc1 = {};

    for (int ks = 0; ks < 32; ++ks) {
        const int k0 = ks * 128;
        #pragma unroll
        for (int c = 0; c < 8; ++c) {
            const int row = c * 16 + ar;
            f16x8 v = *(const f16x8*)(Oa + (size_t)row * HID + k0 + ac);
            *(f16x8*)((char*)sA + swz2(row, ac * 2)) = v;
        }
        {
            const float* wp = Wo + (size_t)(c0 + ar) * HID + k0 + ac;
            float4 x = *(const float4*)wp;
            float4 y = *(const float4*)(wp + 4);
            *(f16x8*)((char*)sB + swz2(ar, ac * 2)) = cvt8(x, y);
        }
        __syncthreads();
        #pragma unroll
        for (int kk = 0; kk < 4; ++kk) {
            const int cb = kk * 64 + (l >> 4) * 16;
            f16x8 a0 = *(const f16x8*)((char*)sA + swz2(rw + (l & 15), cb));
            f16x8 a1 = *(const f16x8*)((char*)sA + swz2(rw + 16 + (l & 15), cb));
            f16x8 b0 = *(const f16x8*)((char*)sB + swz2((l & 15), cb));
            acc0 = MFMA16(a0, b0, acc0);
            acc1 = MFMA16(a1, b0, acc1);
        }
        __syncthreads();
    }
    #pragma unroll
    for (int r = 0; r < 4; ++r) {
        const int col = c0 + (l & 15);
        out[(size_t)(rw + (l >> 4) * 4 + r) * HID + col]      = acc0[r];
        out[(size_t)(rw + 16 + (l >> 4) * 4 + r) * HID + col] = acc1[r];
    }
}

extern "C" void kernel_launch(void* const* d_in, const int* in_sizes, int n_in,
                              void* d_out, int out_size, void* d_ws, size_t ws_size,
                              hipStream_t stream) {
    const float* h  = (const float*)d_in[0];
    const float* Wq = (const float*)d_in[1];
    const float* Wk = (const float*)d_in[2];
    const float* Wv = (const float*)d_in[3];
    const float* Wo = (const float*)d_in[4];
    const float* Kc = (const float*)d_in[5];
    const float* Vc = (const float*)d_in[6];
    const int* pos  = (const int*)d_in[7];
    float* out = (float*)d_out;

    f16* hws = (f16*)d_ws;            // 128*4096 f16 = 1 MB
    f16* Qw  = hws + ROWS * HID;
    f16* Kw  = Qw + ROWS * HID;
    f16* Vw  = Kw + ROWS * HID;
    f16* Ow  = Vw + ROWS * HID;

    k_cvt<<<256, 256, 0, stream>>>(h, hws);
    k_proj<<<768, 256, 0, stream>>>(hws, Wq, Wk, Wv, Qw, Kw, Vw);
    k_attn<<<256, 1024, 0, stream>>>(Qw, Kw, Vw, Kc, Vc, pos, Ow);
    k_oproj<<<256, 256, 0, stream>>>(Ow, Wo, out);
}

// Round 2
// 205.647 us; speedup vs baseline: 1.1731x; 1.1731x over previous
//
#include <hip/hip_runtime.h>

typedef _Float16 f16;
typedef _Float16 f16x8 __attribute__((ext_vector_type(8)));
typedef _Float16 f16x4 __attribute__((ext_vector_type(4)));
typedef _Float16 f16x2 __attribute__((ext_vector_type(2)));
typedef float f32x4 __attribute__((ext_vector_type(4)));
typedef float f32x2 __attribute__((ext_vector_type(2)));

#define MFMA16(a, b, c) __builtin_amdgcn_mfma_f32_16x16x32_f16(a, b, c, 0, 0, 0)

#define HID 4096
#define ROWS 128      // B*S
#define SCL 0.12751743f  // (1/sqrt(128)) * log2(e)

__device__ __forceinline__ f16x8 cvt8(float4 x, float4 y) {
    f16x8 v = {(f16)x.x, (f16)x.y, (f16)x.z, (f16)x.w,
               (f16)y.x, (f16)y.y, (f16)y.z, (f16)y.w};
    return v;
}

// XOR swizzle for a tile with 128 f16 (256 B) row pitch
__device__ __forceinline__ int swz2(int row, int cb) {
    return row * 256 + (cb ^ ((row & 7) << 4));
}

// ---------------- kernel 0: h fp32 -> f16 ----------------
__global__ void k_cvt(const float* __restrict__ src, f16* __restrict__ dst) {
    const int i = blockIdx.x * blockDim.x + threadIdx.x;
    const float4* s4 = (const float4*)src + (size_t)i * 2;
    float4 x = s4[0], y = s4[1];
    *((f16x8*)dst + i) = cvt8(x, y);
}

// ---------------- kernel A: fused QKV projection ----------------
// out[r][c] = sum_k h[r][k] * W[c][k];  M=128, N(tile)=16, K=4096, BK=128
// reg double-buffer: prefetch next K-step's W+h during MFMA phase
__global__ __launch_bounds__(256) void k_proj(
        const f16* __restrict__ hb,
        const float* __restrict__ Wq, const float* __restrict__ Wk,
        const float* __restrict__ Wv,
        f16* __restrict__ Qw, f16* __restrict__ Kw, f16* __restrict__ Vw) {
    const int mat = blockIdx.x >> 8;
    const int ct  = blockIdx.x & 255;
    const float* __restrict__ W = (mat == 0) ? Wq : (mat == 1) ? Wk : Wv;
    f16* __restrict__ Ob = (mat == 0) ? Qw : (mat == 1) ? Kw : Vw;
    const int c0 = ct * 16;

    __shared__ __align__(16) f16 sA[128 * 128];  // 32 KB, swizzled
    __shared__ __align__(16) f16 sB[16 * 128];   // 4 KB, swizzled

    const int tid = threadIdx.x;
    const int w = tid >> 6, l = tid & 63;
    const int rw = w * 32;
    const int ar = tid >> 4;          // 0..15
    const int ac = (tid & 15) * 8;    // element col

    f32x4 acc0 = {}, acc1 = {};

    float4 wx, wy;
    f16x8 hreg[8];
    {
        const float* wp = W + (size_t)(c0 + ar) * HID + ac;
        wx = *(const float4*)wp; wy = *(const float4*)(wp + 4);
        #pragma unroll
        for (int c = 0; c < 8; ++c)
            hreg[c] = *(const f16x8*)(hb + (size_t)(c * 16 + ar) * HID + ac);
    }

    for (int ks = 0; ks < 32; ++ks) {
        // stage current regs -> LDS
        #pragma unroll
        for (int c = 0; c < 8; ++c)
            *(f16x8*)((char*)sA + swz2(c * 16 + ar, ac * 2)) = hreg[c];
        *(f16x8*)((char*)sB + swz2(ar, ac * 2)) = cvt8(wx, wy);
        __syncthreads();
        // prefetch next K-step (in flight during MFMA)
        if (ks < 31) {
            const int k0 = (ks + 1) * 128;
            const float* wp = W + (size_t)(c0 + ar) * HID + k0 + ac;
            wx = *(const float4*)wp; wy = *(const float4*)(wp + 4);
            #pragma unroll
            for (int c = 0; c < 8; ++c)
                hreg[c] = *(const f16x8*)(hb + (size_t)(c * 16 + ar) * HID + k0 + ac);
        }
        #pragma unroll
        for (int kk = 0; kk < 4; ++kk) {
            const int cb = kk * 64 + (l >> 4) * 16;
            f16x8 a0 = *(const f16x8*)((char*)sA + swz2(rw + (l & 15), cb));
            f16x8 a1 = *(const f16x8*)((char*)sA + swz2(rw + 16 + (l & 15), cb));
            f16x8 b0 = *(const f16x8*)((char*)sB + swz2((l & 15), cb));
            acc0 = MFMA16(a0, b0, acc0);
            acc1 = MFMA16(a1, b0, acc1);
        }
        __syncthreads();
    }
    #pragma unroll
    for (int r = 0; r < 4; ++r) {
        const int col = c0 + (l & 15);
        Ob[(size_t)(rw + (l >> 4) * 4 + r) * HID + col]      = (f16)acc0[r];
        Ob[(size_t)(rw + 16 + (l >> 4) * 4 + r) * HID + col] = (f16)acc1[r];
    }
}

// ---------------- kernel B: flash attention, 1 block per (b,h), 8 waves ----------------
__global__ __launch_bounds__(512) void k_attn(
        const f16* __restrict__ Qw, const f16* __restrict__ Kw,
        const f16* __restrict__ Vw,
        const float* __restrict__ Kc, const float* __restrict__ Vc,
        const int* __restrict__ posp, f16* __restrict__ Ow) {

    // smem: during loop -> per-wave P buffers (8 waves * 16x40 f16 = 10 KB)
    //       after loop  -> Osh 64 KB + Msh/Lsh 1 KB (barrier separates uses)
    __shared__ __align__(16) char smem[65536 + 1024];

    const int bh = blockIdx.x;
    const int b = bh >> 5, hh = bh & 31;
    const int tid = threadIdx.x, w = tid >> 6, l = tid & 63;
    const int pos = *posp;
    const int npure = pos >> 5;           // fully-cached 32-row tiles

    const float* Kb = Kc + (size_t)bh * (4096 * 128);
    const float* Vb = Vc + (size_t)bh * (4096 * 128);

    // Q fragments: lane holds Q[s=l&15][d = kk*32 + (l>>4)*8 + j]
    f16x8 qf[4];
    {
        const f16* qp = Qw + (size_t)(b * 16 + (l & 15)) * HID + hh * 128 + (l >> 4) * 8;
        #pragma unroll
        for (int kk = 0; kk < 4; ++kk) qf[kk] = *(const f16x8*)(qp + kk * 32);
    }

    f32x4 o[8] = {};
    float m[4], lsum[4];
    #pragma unroll
    for (int r = 0; r < 4; ++r) { m[r] = -3e38f; lsum[r] = 0.f; }

    f16* Pw = (f16*)smem + w * 640;  // 16 rows x 40 f16 pitch

    // ---- pure (fully-cached) tiles: contiguous even split over 8 waves ----
    const int start = (w * npure) >> 3;
    const int end   = ((w + 1) * npure) >> 3;
    for (int tau = start; tau < end; ++tau) {
        const int t0 = tau << 5;

        // K loads -> f16 frags
        f16x8 kf[2][4];
        #pragma unroll
        for (int tn = 0; tn < 2; ++tn) {
            const float* kp = Kb + (size_t)(t0 + tn * 16 + (l & 15)) * 128 + (l >> 4) * 8;
            #pragma unroll
            for (int kk = 0; kk < 4; ++kk) {
                float4 x = *(const float4*)(kp + kk * 32);
                float4 y = *(const float4*)(kp + kk * 32 + 4);
                kf[tn][kk] = cvt8(x, y);
            }
        }
        // QK^T
        f32x4 sa[2] = {};
        #pragma unroll
        for (int tn = 0; tn < 2; ++tn)
            #pragma unroll
            for (int kk = 0; kk < 4; ++kk) sa[tn] = MFMA16(qf[kk], kf[tn][kk], sa[tn]);

        // V gather issued now; latency hides under softmax + P transpose
        f16x8 vf[8];
        {
            const float* vp = Vb + (size_t)(t0 + (l >> 4) * 8) * 128 + (l & 15);
            #pragma unroll
            for (int dt = 0; dt < 8; ++dt)
                #pragma unroll
                for (int j = 0; j < 8; ++j) vf[dt][j] = (f16)vp[j * 128 + dt * 16];
        }

        // online softmax (no masking on pure tiles)
        float sc[2][4];
        #pragma unroll
        for (int tn = 0; tn < 2; ++tn)
            #pragma unroll
            for (int r = 0; r < 4; ++r) sc[tn][r] = sa[tn][r] * SCL;
        float vmax[4];
        #pragma unroll
        for (int r = 0; r < 4; ++r) vmax[r] = fmaxf(sc[0][r], sc[1][r]);
        #pragma unroll
        for (int d = 1; d < 16; d <<= 1)
            #pragma unroll
            for (int r = 0; r < 4; ++r) vmax[r] = fmaxf(vmax[r], __shfl_xor(vmax[r], d));
        float p[2][4], rs[4], fac[4];
        #pragma unroll
        for (int r = 0; r < 4; ++r) {
            const float mn = fmaxf(m[r], vmax[r]);
            fac[r] = exp2f(m[r] - mn);
            m[r] = mn;
            p[0][r] = exp2f(sc[0][r] - mn);
            p[1][r] = exp2f(sc[1][r] - mn);
            rs[r] = p[0][r] + p[1][r];
            lsum[r] *= fac[r];
        }
        #pragma unroll
        for (int d = 1; d < 16; d <<= 1)
            #pragma unroll
            for (int r = 0; r < 4; ++r) rs[r] += __shfl_xor(rs[r], d);
        #pragma unroll
        for (int r = 0; r < 4; ++r) lsum[r] += rs[r];
        #pragma unroll
        for (int dt = 0; dt < 8; ++dt)
            #pragma unroll
            for (int r = 0; r < 4; ++r) o[dt][r] *= fac[r];

        // P: D-layout -> A-frag layout via per-wave LDS
        #pragma unroll
        for (int r = 0; r < 4; ++r) {
            const int s_ = (l >> 4) * 4 + r;
            Pw[s_ * 40 + (l & 15)]      = (f16)p[0][r];
            Pw[s_ * 40 + 16 + (l & 15)] = (f16)p[1][r];
        }
        asm volatile("s_waitcnt lgkmcnt(0)" ::: "memory");
        f16x8 pa = *(const f16x8*)(Pw + (l & 15) * 40 + (l >> 4) * 8);

        // PV
        #pragma unroll
        for (int dt = 0; dt < 8; ++dt) o[dt] = MFMA16(pa, vf[dt], o[dt]);
    }

    // ---- boundary tiles (cache tail + 16 new rows): wave 7 only ----
    if (w == 7) {
        for (int t0 = npure << 5; t0 < pos + 16; t0 += 32) {
            f32x4 sa[2] = {};
            bool tnv[2];
            #pragma unroll
            for (int tn = 0; tn < 2; ++tn) {
                tnv[tn] = (t0 + tn * 16 < pos + 16);
                if (!tnv[tn]) continue;
                const int trow = t0 + tn * 16 + (l & 15);
                f16x8 kf[4];
                if (trow < pos) {
                    const float* kp = Kb + (size_t)trow * 128 + (l >> 4) * 8;
                    #pragma unroll
                    for (int kk = 0; kk < 4; ++kk) {
                        float4 x = *(const float4*)(kp + kk * 32);
                        float4 y = *(const float4*)(kp + kk * 32 + 4);
                        kf[kk] = cvt8(x, y);
                    }
                } else {
                    const int tt = trow - pos;
                    const int rr = tt < 15 ? tt : 15;
                    const f16* kp = Kw + (size_t)(b * 16 + rr) * HID + hh * 128 + (l >> 4) * 8;
                    #pragma unroll
                    for (int kk = 0; kk < 4; ++kk) kf[kk] = *(const f16x8*)(kp + kk * 32);
                }
                #pragma unroll
                for (int kk = 0; kk < 4; ++kk) sa[tn] = MFMA16(qf[kk], kf[kk], sa[tn]);
            }

            // scale + causal/validity mask
            float sc[2][4];
            #pragma unroll
            for (int tn = 0; tn < 2; ++tn) {
                const int tg = t0 + tn * 16 + (l & 15);
                #pragma unroll
                for (int r = 0; r < 4; ++r) {
                    if (!tnv[tn]) { sc[tn][r] = -3e38f; continue; }
                    float v = sa[tn][r] * SCL;
                    if (tg >= pos) {
                        const int tt = tg - pos;
                        const int s_ = (l >> 4) * 4 + r;
                        if (tt > s_ || tt >= 16) v = -3e38f;
                    }
                    sc[tn][r] = v;
                }
            }

            float vmax[4];
            #pragma unroll
            for (int r = 0; r < 4; ++r) vmax[r] = fmaxf(sc[0][r], sc[1][r]);
            #pragma unroll
            for (int d = 1; d < 16; d <<= 1)
                #pragma unroll
                for (int r = 0; r < 4; ++r) vmax[r] = fmaxf(vmax[r], __shfl_xor(vmax[r], d));
            float p[2][4], rs[4], fac[4];
            #pragma unroll
            for (int r = 0; r < 4; ++r) {
                const float mn = fmaxf(m[r], vmax[r]);
                fac[r] = exp2f(m[r] - mn);
                m[r] = mn;
                p[0][r] = sc[0][r] < -1e29f ? 0.f : exp2f(sc[0][r] - mn);
                p[1][r] = sc[1][r] < -1e29f ? 0.f : exp2f(sc[1][r] - mn);
                rs[r] = p[0][r] + p[1][r];
                lsum[r] *= fac[r];
            }
            #pragma unroll
            for (int d = 1; d < 16; d <<= 1)
                #pragma unroll
                for (int r = 0; r < 4; ++r) rs[r] += __shfl_xor(rs[r], d);
            #pragma unroll
            for (int r = 0; r < 4; ++r) lsum[r] += rs[r];
            #pragma unroll
            for (int dt = 0; dt < 8; ++dt)
                #pragma unroll
                for (int r = 0; r < 4; ++r) o[dt][r] *= fac[r];

            #pragma unroll
            for (int r = 0; r < 4; ++r) {
                const int s_ = (l >> 4) * 4 + r;
                Pw[s_ * 40 + (l & 15)]      = (f16)p[0][r];
                Pw[s_ * 40 + 16 + (l & 15)] = (f16)p[1][r];
            }
            asm volatile("s_waitcnt lgkmcnt(0)" ::: "memory");
            f16x8 pa = *(const f16x8*)(Pw + (l & 15) * 40 + (l >> 4) * 8);

            const int tb = t0 + (l >> 4) * 8;
            #pragma unroll
            for (int dt = 0; dt < 8; ++dt) {
                f16x8 vf;
                #pragma unroll
                for (int j = 0; j < 8; ++j) {
                    const int t = tb + j;
                    if (t < pos) {
                        vf[j] = (f16)Vb[(size_t)t * 128 + dt * 16 + (l & 15)];
                    } else {
                        const int rr = (t - pos < 15) ? (t - pos) : 15;
                        vf[j] = Vw[(size_t)(b * 16 + rr) * HID + hh * 128 + dt * 16 + (l & 15)];
                    }
                }
                o[dt] = MFMA16(pa, vf, o[dt]);
            }
        }
    }

    // ---- merge 8 per-wave partials ----
    __syncthreads();  // everyone done with Pw region (aliases Osh)
    float* Osh = (float*)smem;                 // [8][16][128]
    float* Msh = (float*)(smem + 65536);       // [8][16]
    float* Lsh = Msh + 128;
    #pragma unroll
    for (int dt = 0; dt < 8; ++dt)
        #pragma unroll
        for (int r = 0; r < 4; ++r)
            Osh[w * 2048 + ((l >> 4) * 4 + r) * 128 + dt * 16 + (l & 15)] = o[dt][r];
    if ((l & 15) == 0) {
        #pragma unroll
        for (int r = 0; r < 4; ++r) {
            Msh[w * 16 + (l >> 4) * 4 + r] = m[r];
            Lsh[w * 16 + (l >> 4) * 4 + r] = lsum[r];
        }
    }
    __syncthreads();
    {
        const int s_ = tid >> 5;           // 0..15
        const int d_ = (tid & 31) * 4;     // 0..124
        float M = -3e38f;
        #pragma unroll
        for (int ww = 0; ww < 8; ++ww) M = fmaxf(M, Msh[ww * 16 + s_]);
        float L = 0.f;
        f32x4 oa = {};
        #pragma unroll
        for (int ww = 0; ww < 8; ++ww) {
            const float e = exp2f(Msh[ww * 16 + s_] - M);
            L += e * Lsh[ww * 16 + s_];
            f32x4 v = *(const f32x4*)(Osh + ww * 2048 + s_ * 128 + d_);
            #pragma unroll
            for (int r = 0; r < 4; ++r) oa[r] += e * v[r];
        }
        const float inv = 1.f / L;
        f16x4 res = {(f16)(oa[0] * inv), (f16)(oa[1] * inv),
                     (f16)(oa[2] * inv), (f16)(oa[3] * inv)};
        *(f16x4*)(Ow + (size_t)(b * 16 + s_) * HID + hh * 128 + d_) = res;
    }
}

// ---------------- kernel C: output projection ----------------
__global__ __launch_bounds__(256) void k_oproj(
        const f16* __restrict__ Oa, const float* __restrict__ Wo,
        float* __restrict__ out) {
    const int c0 = blockIdx.x * 16;

    __shared__ __align__(16) f16 sA[128 * 128];
    __shared__ __align__(16) f16 sB[16 * 128];

    const int tid = threadIdx.x;
    const int w = tid >> 6, l = tid & 63;
    const int rw = w * 32;
    const int ar = tid >> 4;
    const int ac = (tid & 15) * 8;

    f32x4 acc0 = {}, acc1 = {};

    float4 wx, wy;
    f16x8 hreg[8];
    {
        const float* wp = Wo + (size_t)(c0 + ar) * HID + ac;
        wx = *(const float4*)wp; wy = *(const float4*)(wp + 4);
        #pragma unroll
        for (int c = 0; c < 8; ++c)
            hreg[c] = *(const f16x8*)(Oa + (size_t)(c * 16 + ar) * HID + ac);
    }

    for (int ks = 0; ks < 32; ++ks) {
        #pragma unroll
        for (int c = 0; c < 8; ++c)
            *(f16x8*)((char*)sA + swz2(c * 16 + ar, ac * 2)) = hreg[c];
        *(f16x8*)((char*)sB + swz2(ar, ac * 2)) = cvt8(wx, wy);
        __syncthreads();
        if (ks < 31) {
            const int k0 = (ks + 1) * 128;
            const float* wp = Wo + (size_t)(c0 + ar) * HID + k0 + ac;
            wx = *(const float4*)wp; wy = *(const float4*)(wp + 4);
            #pragma unroll
            for (int c = 0; c < 8; ++c)
                hreg[c] = *(const f16x8*)(Oa + (size_t)(c * 16 + ar) * HID + k0 + ac);
        }
        #pragma unroll
        for (int kk = 0; kk < 4; ++kk) {
            const int cb = kk * 64 + (l >> 4) * 16;
            f16x8 a0 = *(const f16x8*)((char*)sA + swz2(rw + (l & 15), cb));
            f16x8 a1 = *(const f16x8*)((char*)sA + swz2(rw + 16 + (l & 15), cb));
            f16x8 b0 = *(const f16x8*)((char*)sB + swz2((l & 15), cb));
            acc0 = MFMA16(a0, b0, acc0);
            acc1 = MFMA16(a1, b0, acc1);
        }
        __syncthreads();
    }
    #pragma unroll
    for (int r = 0; r < 4; ++r) {
        const int col = c0 + (l & 15);
        out[(size_t)(rw + (l >> 4) * 4 + r) * HID + col]      = acc0[r];
        out[(size_t)(rw + 16 + (l >> 4) * 4 + r) * HID + col] = acc1[r];
    }
}

extern "C" void kernel_launch(void* const* d_in, const int* in_sizes, int n_in,
                              void* d_out, int out_size, void* d_ws, size_t ws_size,
                              hipStream_t stream) {
    const float* h  = (const float*)d_in[0];
    const float* Wq = (const float*)d_in[1];
    const float* Wk = (const float*)d_in[2];
    const float* Wv = (const float*)d_in[3];
    const float* Wo = (const float*)d_in[4];
    const float* Kc = (const float*)d_in[5];
    const float* Vc = (const float*)d_in[6];
    const int* pos  = (const int*)d_in[7];
    float* out = (float*)d_out;

    f16* hws = (f16*)d_ws;            // 128*4096 f16 = 1 MB
    f16* Qw  = hws + ROWS * HID;
    f16* Kw  = Qw + ROWS * HID;
    f16* Vw  = Kw + ROWS * HID;
    f16* Ow  = Vw + ROWS * HID;

    k_cvt<<<256, 256, 0, stream>>>(h, hws);
    k_proj<<<768, 256, 0, stream>>>(hws, Wq, Wk, Wv, Qw, Kw, Vw);
    k_attn<<<256, 512, 0, stream>>>(Qw, Kw, Vw, Kc, Vc, pos, Ow);
    k_oproj<<<256, 256, 0, stream>>>(Ow, Wo, out);
}